// Round 1
// baseline (637.082 us; speedup 1.0000x reference)
//
#include <hip/hip_runtime.h>
#include <hip/hip_bf16.h>
#include <math.h>

typedef __bf16 bf16;
typedef __bf16 bf16x8 __attribute__((ext_vector_type(8)));
typedef __bf16 bf16x4 __attribute__((ext_vector_type(4)));
typedef float  f32x4  __attribute__((ext_vector_type(4)));

static constexpr int B_  = 2;
static constexpr int S_  = 2048;
static constexpr int D_  = 1024;
static constexpr int H_  = 16;
static constexpr int HD_ = 64;
static constexpr int I_  = 4096;
static constexpr int NT  = B_ * S_;       // 4096 tokens

// ---------- helpers ----------
__device__ __forceinline__ void atomicMaxF(float* p, float v) {
  // v >= 0 always (absmax), so uint bit-order == float order
  atomicMax((unsigned int*)p, __float_as_uint(v));
}

__device__ __forceinline__ f32x4 mfma16(bf16x8 a, bf16x8 b, f32x4 c) {
  return __builtin_amdgcn_mfma_f32_16x16x32_bf16(a, b, c, 0, 0, 0);
}

__device__ __forceinline__ void gload16(const void* g, void* lds) {
  // async global->LDS, 16B/lane; LDS dest = wave-uniform base + lane*16
  __builtin_amdgcn_global_load_lds(
      (const __attribute__((address_space(1))) void*)g,
      (__attribute__((address_space(3))) void*)lds, 16, 0, 0);
}

__device__ __forceinline__ float quant1(float x, float scale, float qmax) {
  // matches jnp: round(clip(x/scale,-qmax,qmax))*scale, RNE rounding
  return rintf(fminf(fmaxf(x / scale, -qmax), qmax)) * scale;
}

// ---------- scalar init ----------
__global__ void k_init(float* s) {
  if (threadIdx.x < 32) s[threadIdx.x] = 0.f;
}

// ---------- per-tensor absmax (fp32 input) ----------
__global__ __launch_bounds__(256) void k_absmax(const float* __restrict__ x, size_t n4,
                                                float* __restrict__ slot) {
  size_t i = (size_t)blockIdx.x * 256 + threadIdx.x;
  const size_t stride = (size_t)gridDim.x * 256;
  float m = 0.f;
  for (; i < n4; i += stride) {
    float4 v = ((const float4*)x)[i];
    m = fmaxf(m, fmaxf(fmaxf(fabsf(v.x), fabsf(v.y)), fmaxf(fabsf(v.z), fabsf(v.w))));
  }
  #pragma unroll
  for (int o = 32; o; o >>= 1) m = fmaxf(m, __shfl_xor(m, o));
  __shared__ float red[4];
  if ((threadIdx.x & 63) == 0) red[threadIdx.x >> 6] = m;
  __syncthreads();
  if (threadIdx.x == 0)
    atomicMaxF(slot, fmaxf(fmaxf(red[0], red[1]), fmaxf(red[2], red[3])));
}

// ---------- fake-quant fp32 -> bf16 ----------
__global__ __launch_bounds__(256) void k_quant(const float* __restrict__ x, bf16* __restrict__ y,
                                               const float* __restrict__ slot,
                                               const int* __restrict__ bits, size_t n4) {
  const float qmax  = (float)((1 << (*bits - 1)) - 1);
  const float scale = fmaxf(*slot, 1e-8f) / qmax;
  size_t i = (size_t)blockIdx.x * 256 + threadIdx.x;
  const size_t stride = (size_t)gridDim.x * 256;
  for (; i < n4; i += stride) {
    float4 v = ((const float4*)x)[i];
    bf16x4 o;
    o[0] = (bf16)quant1(v.x, scale, qmax);
    o[1] = (bf16)quant1(v.y, scale, qmax);
    o[2] = (bf16)quant1(v.z, scale, qmax);
    o[3] = (bf16)quant1(v.w, scale, qmax);
    ((bf16x4*)y)[i] = o;
  }
}

// ---------- fake-quant bf16 in-place (GELU output) ----------
__global__ __launch_bounds__(256) void k_quant_ip(bf16* __restrict__ x,
                                                  const float* __restrict__ slot,
                                                  const int* __restrict__ bits, size_t n8) {
  const float qmax  = (float)((1 << (*bits - 1)) - 1);
  const float scale = fmaxf(*slot, 1e-8f) / qmax;
  size_t i = (size_t)blockIdx.x * 256 + threadIdx.x;
  if (i >= n8) return;
  bf16x8 v = ((const bf16x8*)x)[i];
  #pragma unroll
  for (int j = 0; j < 8; j++) v[j] = (bf16)quant1((float)v[j], scale, qmax);
  ((bf16x8*)x)[i] = v;
}

// ---------- LayerNorm (fp32 out, + absmax) : one block per row ----------
__global__ __launch_bounds__(256) void k_ln(const float* __restrict__ x, const float* __restrict__ g,
                                            const float* __restrict__ be, float* __restrict__ y,
                                            float* __restrict__ slot) {
  const int row = blockIdx.x, t = threadIdx.x;
  const float4 v = ((const float4*)(x + (size_t)row * D_))[t];
  float s = v.x + v.y + v.z + v.w;
  float q = v.x * v.x + v.y * v.y + v.z * v.z + v.w * v.w;
  #pragma unroll
  for (int o = 32; o; o >>= 1) { s += __shfl_xor(s, o); q += __shfl_xor(q, o); }
  __shared__ float red[8];
  const int wid = t >> 6;
  if ((t & 63) == 0) { red[wid] = s; red[4 + wid] = q; }
  __syncthreads();
  s = red[0] + red[1] + red[2] + red[3];
  q = red[4] + red[5] + red[6] + red[7];
  const float mean = s * (1.f / D_);
  const float rstd = rsqrtf(q * (1.f / D_) - mean * mean + 1e-5f);
  const float4 gv = ((const float4*)g)[t];
  const float4 bv = ((const float4*)be)[t];
  float4 o;
  o.x = (v.x - mean) * rstd * gv.x + bv.x;
  o.y = (v.y - mean) * rstd * gv.y + bv.y;
  o.z = (v.z - mean) * rstd * gv.z + bv.z;
  o.w = (v.w - mean) * rstd * gv.w + bv.w;
  ((float4*)(y + (size_t)row * D_))[t] = o;
  float m = fmaxf(fmaxf(fabsf(o.x), fabsf(o.y)), fmaxf(fabsf(o.z), fabsf(o.w)));
  #pragma unroll
  for (int oo = 32; oo; oo >>= 1) m = fmaxf(m, __shfl_xor(m, oo));
  __syncthreads();                 // red reuse
  if ((t & 63) == 0) red[wid] = m;
  __syncthreads();
  if (t == 0) atomicMaxF(slot, fmaxf(fmaxf(red[0], red[1]), fmaxf(red[2], red[3])));
}

// ---------- GEMM: C[M,N] = A[M,K] @ B[N,K]^T (+bias, +mode epilogue) ----------
// 128x128 tile, BK=32, 4 waves in 2x2, each wave 64x64 = 4x4 mfma_16x16x32 frags.
struct GemmArgs {
  const bf16* A;
  const bf16* B0; const bf16* B1; const bf16* B2;
  const float* bias0; const float* bias1; const float* bias2;
  void* out0; void* out1; void* out2;
  const float* res;   // MODE 1: residual (fp32, same layout as out)
  float* slot;        // MODE 2: absmax slot
  int K; int ldc;
};

// MODE 0: bf16 out (+bias), 3-way select by blockIdx.z (QKV fused)
// MODE 1: f32 out = acc + bias + res
// MODE 2: bf16 out = gelu(acc+bias), absmax -> slot
template <int MODE>
__global__ __launch_bounds__(256) void k_gemm(GemmArgs a) {
  __shared__ __align__(16) bf16 As[128 * 32];
  __shared__ __align__(16) bf16 Bs[128 * 32];
  const int t = threadIdx.x, wid = t >> 6, lane = t & 63;
  const int grp = lane >> 4, l15 = lane & 15;
  const int wm = wid >> 1, wn = wid & 1;
  const size_t m0 = (size_t)blockIdx.x * 128, n0 = (size_t)blockIdx.y * 128;
  const int K = a.K, ldc = a.ldc;

  const bf16* Bw; const float* bias; void* outv;
  if constexpr (MODE == 0) {
    const int z = blockIdx.z;
    Bw   = z == 0 ? a.B0 : (z == 1 ? a.B1 : a.B2);
    bias = z == 0 ? a.bias0 : (z == 1 ? a.bias1 : a.bias2);
    outv = z == 0 ? a.out0 : (z == 1 ? a.out1 : a.out2);
  } else {
    Bw = a.B0; bias = a.bias0; outv = a.out0;
  }

  const f32x4 zero = {0.f, 0.f, 0.f, 0.f};
  f32x4 acc[4][4];
  #pragma unroll
  for (int m = 0; m < 4; m++)
    #pragma unroll
    for (int n = 0; n < 4; n++) acc[m][n] = zero;

  for (int kt = 0; kt < K; kt += 32) {
    // stage A,B tiles (8KB each): 4 waves x 2 rounds x 1KB
    #pragma unroll
    for (int r = 0; r < 2; r++) {
      const int ob  = (wid * 2 + r) * 1024 + lane * 16;  // byte in tile
      const int row = ob >> 6;                            // 64B per row (32 bf16)
      const int col = (ob & 63) >> 1;
      gload16(a.A + (m0 + row) * (size_t)K + (kt + col), (char*)As + (size_t)(wid * 2 + r) * 1024);
      gload16(Bw  + (n0 + row) * (size_t)K + (kt + col), (char*)Bs + (size_t)(wid * 2 + r) * 1024);
    }
    __syncthreads();   // drains vmcnt (global_load_lds) + lgkm
    bf16x8 af[4], bfv[4];
    #pragma unroll
    for (int m = 0; m < 4; m++)
      af[m] = *(const bf16x8*)(As + (wm * 64 + m * 16 + l15) * 32 + grp * 8);
    #pragma unroll
    for (int n = 0; n < 4; n++)
      bfv[n] = *(const bf16x8*)(Bs + (wn * 64 + n * 16 + l15) * 32 + grp * 8);
    #pragma unroll
    for (int m = 0; m < 4; m++)
      #pragma unroll
      for (int n = 0; n < 4; n++)
        acc[m][n] = mfma16(af[m], bfv[n], acc[m][n]);
    __syncthreads();   // protect LDS before next stage
  }

  // epilogue: C/D frag layout: row=(lane>>4)*4+i, col=lane&15
  const size_t gr0 = m0 + wm * 64 + grp * 4;
  const size_t gc0 = n0 + wn * 64 + l15;
  float lmax = 0.f;
  #pragma unroll
  for (int n = 0; n < 4; n++) {
    const size_t gc = gc0 + n * 16;
    const float bc = bias[gc];
    #pragma unroll
    for (int m = 0; m < 4; m++) {
      const size_t gr = gr0 + m * 16;
      #pragma unroll
      for (int i = 0; i < 4; i++) {
        const float v = acc[m][n][i] + bc;
        const size_t idx = (gr + i) * (size_t)ldc + gc;
        if constexpr (MODE == 0) {
          ((bf16*)outv)[idx] = (bf16)v;
        } else if constexpr (MODE == 1) {
          ((float*)outv)[idx] = v + a.res[idx];
        } else {
          const float gl = 0.5f * v * (1.0f + erff(v * 0.7071067811865475f));
          ((bf16*)outv)[idx] = (bf16)gl;
          lmax = fmaxf(lmax, fabsf(gl));
        }
      }
    }
  }
  if constexpr (MODE == 2) {
    #pragma unroll
    for (int o = 32; o; o >>= 1) lmax = fmaxf(lmax, __shfl_xor(lmax, o));
    __shared__ float red[4];
    if (lane == 0) red[wid] = lmax;
    __syncthreads();
    if (t == 0) atomicMaxF(a.slot, fmaxf(fmaxf(red[0], red[1]), fmaxf(red[2], red[3])));
  }
}

// ---------- fused attention (flash-style), fp32 out + absmax ----------
// block = 4 waves, 64 q-rows (16/wave); K/V tiles of 64; online softmax.
__global__ __launch_bounds__(256) void k_attn(const bf16* __restrict__ qb, const bf16* __restrict__ kb,
                                              const bf16* __restrict__ vb, const float* __restrict__ mask,
                                              float* __restrict__ out, float* __restrict__ slot) {
  constexpr int PAD = 72;  // 64+8: breaks the 128B-stride bank conflict, keeps 16B align
  __shared__ __align__(16) bf16 Vt[64 * PAD];        // V^T : [hd][key]
  __shared__ __align__(16) bf16 Ps[4][16 * PAD];     // per-wave P : [qrow][key]
  __shared__ float red[4];
  const int t = threadIdx.x, wid = t >> 6, lane = t & 63;
  const int grp = lane >> 4, l15 = lane & 15;
  const int qt = blockIdx.x, bh = blockIdx.y;
  const int b = bh >> 4, h = bh & 15;                // H = 16
  const size_t base = ((size_t)b * S_) * D_ + (size_t)h * HD_;
  const int q0 = qt * 64 + wid * 16;

  bf16x8 qf[2];
  #pragma unroll
  for (int c = 0; c < 2; c++)
    qf[c] = *(const bf16x8*)(qb + base + (size_t)(q0 + l15) * D_ + c * 32 + grp * 8);

  const f32x4 zero = {0.f, 0.f, 0.f, 0.f};
  f32x4 ao[4];
  #pragma unroll
  for (int nf = 0; nf < 4; nf++) ao[nf] = zero;
  float mi[4], li[4];
  #pragma unroll
  for (int i = 0; i < 4; i++) { mi[i] = -INFINITY; li[i] = 0.f; }

  for (int kt0 = 0; kt0 < S_; kt0 += 64) {
    __syncthreads();   // previous iter's Vt readers done
    {  // stage V^T: thread t covers key k0, hd [hd0, hd0+16)
      const int k0 = t >> 2, hd0 = (t & 3) << 4;
      const bf16* vs = vb + base + (size_t)(kt0 + k0) * D_ + hd0;
      const bf16x8 va = *(const bf16x8*)vs;
      const bf16x8 vbb = *(const bf16x8*)(vs + 8);
      #pragma unroll
      for (int e = 0; e < 8; e++) Vt[(hd0 + e) * PAD + k0] = va[e];
      #pragma unroll
      for (int e = 0; e < 8; e++) Vt[(hd0 + 8 + e) * PAD + k0] = vbb[e];
    }
    // QK^T : 16x64 scores per wave
    f32x4 accs[4];
    float madd[4];
    #pragma unroll
    for (int nf = 0; nf < 4; nf++) {
      const bf16* kp = kb + base + (size_t)(kt0 + nf * 16 + l15) * D_ + grp * 8;
      const bf16x8 k0f = *(const bf16x8*)kp;
      const bf16x8 k1f = *(const bf16x8*)(kp + 32);
      f32x4 z = zero;
      z = mfma16(qf[0], k0f, z);
      z = mfma16(qf[1], k1f, z);
      accs[nf] = z;
      madd[nf] = (1.0f - mask[(size_t)b * S_ + kt0 + nf * 16 + l15]) * -10000.0f;
    }
    // online softmax (rows live in 16-lane groups; 4 rows/lane via reg i)
    float p[4][4], corr[4];
    #pragma unroll
    for (int i = 0; i < 4; i++) {
      float s0 = fmaxf(fmaxf(accs[0][i] * 0.125f + madd[0], accs[1][i] * 0.125f + madd[1]),
                       fmaxf(accs[2][i] * 0.125f + madd[2], accs[3][i] * 0.125f + madd[3]));
      s0 = fmaxf(s0, __shfl_xor(s0, 1));
      s0 = fmaxf(s0, __shfl_xor(s0, 2));
      s0 = fmaxf(s0, __shfl_xor(s0, 4));
      s0 = fmaxf(s0, __shfl_xor(s0, 8));
      const float mnew = fmaxf(mi[i], s0);
      corr[i] = __expf(mi[i] - mnew);
      float rs = 0.f;
      #pragma unroll
      for (int nf = 0; nf < 4; nf++) {
        const float pv = __expf(accs[nf][i] * 0.125f + madd[nf] - mnew);
        p[nf][i] = pv; rs += pv;
      }
      rs += __shfl_xor(rs, 1); rs += __shfl_xor(rs, 2);
      rs += __shfl_xor(rs, 4); rs += __shfl_xor(rs, 8);
      li[i] = li[i] * corr[i] + rs;
      mi[i] = mnew;
    }
    #pragma unroll
    for (int nf = 0; nf < 4; nf++) {
      f32x4 aa = ao[nf];
      aa[0] *= corr[0]; aa[1] *= corr[1]; aa[2] *= corr[2]; aa[3] *= corr[3];
      ao[nf] = aa;
      #pragma unroll
      for (int i = 0; i < 4; i++)
        Ps[wid][(grp * 4 + i) * PAD + nf * 16 + l15] = (bf16)p[nf][i];
    }
    __syncthreads();   // Vt staged + Ps visible
    // P @ V
    #pragma unroll
    for (int c = 0; c < 2; c++) {
      const bf16x8 ap = *(const bf16x8*)(&Ps[wid][l15 * PAD + c * 32 + grp * 8]);
      #pragma unroll
      for (int nf = 0; nf < 4; nf++) {
        const bf16x8 bv = *(const bf16x8*)(&Vt[(nf * 16 + l15) * PAD + c * 32 + grp * 8]);
        ao[nf] = mfma16(ap, bv, ao[nf]);
      }
    }
  }
  // epilogue: normalize, write fp32, absmax
  float lmax = 0.f;
  #pragma unroll
  for (int nf = 0; nf < 4; nf++) {
    #pragma unroll
    for (int i = 0; i < 4; i++) {
      const float o = ao[nf][i] / li[i];
      out[base + (size_t)(q0 + grp * 4 + i) * D_ + nf * 16 + l15] = o;
      lmax = fmaxf(lmax, fabsf(o));
    }
  }
  #pragma unroll
  for (int o = 32; o; o >>= 1) lmax = fmaxf(lmax, __shfl_xor(lmax, o));
  if (lane == 0) red[wid] = lmax;
  __syncthreads();
  if (t == 0) atomicMaxF(slot, fmaxf(fmaxf(red[0], red[1]), fmaxf(red[2], red[3])));
}

// ---------- launch ----------
extern "C" void kernel_launch(void* const* d_in, const int* in_sizes, int n_in,
                              void* d_out, int out_size, void* d_ws, size_t ws_size,
                              hipStream_t stream) {
  const float* hs   = (const float*)d_in[0];
  const float* mask = (const float*)d_in[1];
  const float* wq = (const float*)d_in[2];  const float* bq = (const float*)d_in[3];
  const float* wk = (const float*)d_in[4];  const float* bk = (const float*)d_in[5];
  const float* wv = (const float*)d_in[6];  const float* bv = (const float*)d_in[7];
  const float* wo = (const float*)d_in[8];  const float* bo = (const float*)d_in[9];
  const float* w1 = (const float*)d_in[10]; const float* b1 = (const float*)d_in[11];
  const float* w2 = (const float*)d_in[12]; const float* b2 = (const float*)d_in[13];
  const float* g1 = (const float*)d_in[14]; const float* be1 = (const float*)d_in[15];
  const float* g2 = (const float*)d_in[16]; const float* be2 = (const float*)d_in[17];
  const int* wbits = (const int*)d_in[18];
  const int* abits = (const int*)d_in[19];

  // workspace layout (bytes)
  char* ws = (char*)d_ws;
  size_t off = 0;
  float* scal = (float*)ws;                      off += 256;        // absmax slots
  float* fbuf = (float*)(ws + off);              off += (size_t)NT * D_ * 4;  // x1f/attnf/x2f
  bf16*  qx   = (bf16*)(ws + off);               off += (size_t)NT * D_ * 2;  // x1q/attnq/x2q
  bf16*  qb   = (bf16*)(ws + off);               off += (size_t)NT * D_ * 2;
  bf16*  kbuf = (bf16*)(ws + off);               off += (size_t)NT * D_ * 2;
  bf16*  vbuf = (bf16*)(ws + off);               off += (size_t)NT * D_ * 2;
  float* h2   = (float*)(ws + off);              off += (size_t)NT * D_ * 4;  // attn residual out
  bf16*  h1   = (bf16*)(ws + off);               off += (size_t)NT * I_ * 2;  // gelu out (quant ip)
  bf16*  wqq  = (bf16*)(ws + off);               off += (size_t)D_ * D_ * 2;
  bf16*  wkq  = (bf16*)(ws + off);               off += (size_t)D_ * D_ * 2;
  bf16*  wvq  = (bf16*)(ws + off);               off += (size_t)D_ * D_ * 2;
  bf16*  woq  = (bf16*)(ws + off);               off += (size_t)D_ * D_ * 2;
  bf16*  w1q  = (bf16*)(ws + off);               off += (size_t)I_ * D_ * 2;
  bf16*  w2q  = (bf16*)(ws + off);               off += (size_t)D_ * I_ * 2;
  if (ws_size < off) return;  // insufficient workspace: fail cleanly

  // slots: 0 x1, 1 attn, 2 x2, 3 h1, 4..9 weights
  k_init<<<1, 64, 0, stream>>>(scal);

  const size_t nDD4 = (size_t)D_ * D_ / 4, nDI4 = (size_t)D_ * I_ / 4;
  k_absmax<<<1024, 256, 0, stream>>>(wq, nDD4, scal + 4);
  k_absmax<<<1024, 256, 0, stream>>>(wk, nDD4, scal + 5);
  k_absmax<<<1024, 256, 0, stream>>>(wv, nDD4, scal + 6);
  k_absmax<<<1024, 256, 0, stream>>>(wo, nDD4, scal + 7);
  k_absmax<<<1024, 256, 0, stream>>>(w1, nDI4, scal + 8);
  k_absmax<<<1024, 256, 0, stream>>>(w2, nDI4, scal + 9);
  k_quant<<<1024, 256, 0, stream>>>(wq, wqq, scal + 4, wbits, nDD4);
  k_quant<<<1024, 256, 0, stream>>>(wk, wkq, scal + 5, wbits, nDD4);
  k_quant<<<1024, 256, 0, stream>>>(wv, wvq, scal + 6, wbits, nDD4);
  k_quant<<<1024, 256, 0, stream>>>(wo, woq, scal + 7, wbits, nDD4);
  k_quant<<<1024, 256, 0, stream>>>(w1, w1q, scal + 8, wbits, nDI4);
  k_quant<<<1024, 256, 0, stream>>>(w2, w2q, scal + 9, wbits, nDI4);

  const size_t nND4 = (size_t)NT * D_ / 4;

  // LN1 -> fake-quant -> fused QKV GEMM
  k_ln<<<NT, 256, 0, stream>>>(hs, g1, be1, fbuf, scal + 0);
  k_quant<<<2048, 256, 0, stream>>>(fbuf, qx, scal + 0, abits, nND4);
  {
    GemmArgs ga{};
    ga.A = qx; ga.B0 = wqq; ga.B1 = wkq; ga.B2 = wvq;
    ga.bias0 = bq; ga.bias1 = bk; ga.bias2 = bv;
    ga.out0 = qb; ga.out1 = kbuf; ga.out2 = vbuf;
    ga.K = D_; ga.ldc = D_;
    k_gemm<0><<<dim3(NT / 128, D_ / 128, 3), 256, 0, stream>>>(ga);
  }

  // attention -> fake-quant -> out-proj (+residual)
  k_attn<<<dim3(S_ / 64, B_ * H_), 256, 0, stream>>>(qb, kbuf, vbuf, mask, fbuf, scal + 1);
  k_quant<<<2048, 256, 0, stream>>>(fbuf, qx, scal + 1, abits, nND4);
  {
    GemmArgs ga{};
    ga.A = qx; ga.B0 = woq; ga.bias0 = bo; ga.out0 = h2; ga.res = hs;
    ga.K = D_; ga.ldc = D_;
    k_gemm<1><<<dim3(NT / 128, D_ / 128), 256, 0, stream>>>(ga);
  }

  // LN2 -> fake-quant -> MLP1 (gelu + absmax) -> fake-quant -> MLP2 (+residual)
  k_ln<<<NT, 256, 0, stream>>>(h2, g2, be2, fbuf, scal + 2);
  k_quant<<<2048, 256, 0, stream>>>(fbuf, qx, scal + 2, abits, nND4);
  {
    GemmArgs ga{};
    ga.A = qx; ga.B0 = w1q; ga.bias0 = b1; ga.out0 = h1; ga.slot = scal + 3;
    ga.K = D_; ga.ldc = I_;
    k_gemm<2><<<dim3(NT / 128, I_ / 128), 256, 0, stream>>>(ga);
  }
  k_quant_ip<<<(NT * (size_t)I_ / 8 + 255) / 256, 256, 0, stream>>>(h1, scal + 3, abits,
                                                                    (size_t)NT * I_ / 8);
  {
    GemmArgs ga{};
    ga.A = h1; ga.B0 = w2q; ga.bias0 = b2; ga.out0 = d_out; ga.res = h2;
    ga.K = I_; ga.ldc = D_;
    k_gemm<1><<<dim3(NT / 128, D_ / 128), 256, 0, stream>>>(ga);
  }
}